// Round 7
// baseline (3335.672 us; speedup 1.0000x reference)
//
#include <hip/hip_runtime.h>

// ---------------------------------------------------------------------------
// Self_RNN forward, MI355X.
//   Wrv = Wrec@Wv ; Wrk = Wrec@Wk ; Wrq = Wrec@Wq ; Wkq = Wrk@Wrq^T
//   WgT = Wrk@Wq^T ; G[b,t] = x[b,t]@WgT^T ; XV[b,t] = x[b,t]@Wv
//   per step: y = h @ [Wrv | Wkq]  -> Vh = y[0:512], q = y[512:1024]
//             s0=(q.h)sc, s1=(h.G[t-1])sc, s2=(h.G[t])sc ; a=softmax(s)
//             h' = a0*Vh + a1*XV[t-1] + a2*XV[t]
// Sequential phase: 256 coop WGs = 8 groups (8 chains) x 32 slices (32 cols),
// wg = s*8+g so each group lives on one XCD. Matvec via MFMA 16x16x32 f16
// (chains = rows 0-7, rows 8-15 zero), K split across 4 waves, LDS reduce.
// Sync = tagged u64; Vh published as {tag, 2xf16}; q-slices publish one
// s0-partial scalar per chain. s1/s2 on waves 1-2 off the critical path.
// ---------------------------------------------------------------------------

typedef _Float16 f16;
typedef _Float16 half8 __attribute__((ext_vector_type(8)));
typedef _Float16 h2 __attribute__((ext_vector_type(2)));
typedef float floatx4 __attribute__((ext_vector_type(4)));
typedef unsigned long long u64;

#define AM_F32 0
#define AM_F16 1
#define BM_NN_F32 0   // B  is [K][N] f32 (transpose-staged)
#define BM_BT_F16 1   // Bt is [N][K] f16
#define BM_BT_F32 2   // Bt is [N][K] f32

#if defined(__has_builtin)
#if __has_builtin(__builtin_amdgcn_fdot2)
#define HAS_FDOT2 1
#endif
#endif

__device__ inline float dot2f(h2 a, h2 b, float c) {
#ifdef HAS_FDOT2
  return __builtin_amdgcn_fdot2(a, b, c, false);
#else
  return c + (float)a[0] * (float)b[0] + (float)a[1] * (float)b[1];
#endif
}

// C[M,N] = A[M,K] @ B ; 128x128 tile, BK=32, 4 waves, MFMA f16.
// CT=0: C[row*ldc + coff + col]   CT=1: C[(coff+col)*ldc + row]
template<int AMODE, int BMODE, int CT>
__global__ __launch_bounds__(256)
void gemm128(const void* __restrict__ Ap, const void* __restrict__ Bp,
             f16* __restrict__ C, int K, int ldbnn, long ldc, long coff,
             int ntiles) {
  __shared__ f16 Al[128 * 32];
  __shared__ f16 Bl[128 * 32];
  const int tid = threadIdx.x;
  const int lane = tid & 63;
  const int wid = tid >> 6;
  const int wr = wid >> 1, wc = wid & 1;
  const int mt = blockIdx.x / ntiles, nt = blockIdx.x % ntiles;
  const long m0 = (long)mt * 128, n0 = (long)nt * 128;

  floatx4 acc[4][4];
#pragma unroll
  for (int m = 0; m < 4; ++m)
#pragma unroll
    for (int n = 0; n < 4; ++n) acc[m][n] = (floatx4){0.f, 0.f, 0.f, 0.f};

  for (int k0 = 0; k0 < K; k0 += 32) {
    __syncthreads();
#pragma unroll
    for (int i = 0; i < 2; ++i) {
      const int slot = i * 256 + tid;
      const int row = slot >> 2;
      const int kc = (slot & 3) * 8;
      if constexpr (AMODE == AM_F16) {
        const f16* Ag = (const f16*)Ap;
        half8 v = *(const half8*)(Ag + (m0 + row) * (long)K + k0 + kc);
        *(half8*)(Al + slot * 8) = v;
      } else {
        const float* Ag = (const float*)Ap;
        const float* p = Ag + (m0 + row) * (long)K + k0 + kc;
        float4 v0 = *(const float4*)(p);
        float4 v1 = *(const float4*)(p + 4);
        half8 h;
        h[0] = (f16)v0.x; h[1] = (f16)v0.y; h[2] = (f16)v0.z; h[3] = (f16)v0.w;
        h[4] = (f16)v1.x; h[5] = (f16)v1.y; h[6] = (f16)v1.z; h[7] = (f16)v1.w;
        *(half8*)(Al + slot * 8) = h;
      }
    }
    if constexpr (BMODE == BM_NN_F32) {
      const float* Bg = (const float*)Bp;
      const int nn = tid & 127;
      const int kh = (tid >> 7) * 16;
#pragma unroll
      for (int j = 0; j < 16; j += 2) {
        float b0 = Bg[(long)(k0 + kh + j) * ldbnn + n0 + nn];
        float b1 = Bg[(long)(k0 + kh + j + 1) * ldbnn + n0 + nn];
        h2 hv; hv[0] = (f16)b0; hv[1] = (f16)b1;
        *(h2*)(Bl + nn * 32 + kh + j) = hv;
      }
    } else {
#pragma unroll
      for (int i = 0; i < 2; ++i) {
        const int slot = i * 256 + tid;
        const int row = slot >> 2;
        const int kc = (slot & 3) * 8;
        if constexpr (BMODE == BM_BT_F16) {
          const f16* Bg = (const f16*)Bp;
          half8 v = *(const half8*)(Bg + (n0 + row) * (long)K + k0 + kc);
          *(half8*)(Bl + slot * 8) = v;
        } else {
          const float* Bg = (const float*)Bp;
          const float* p = Bg + (n0 + row) * (long)K + k0 + kc;
          float4 v0 = *(const float4*)(p);
          float4 v1 = *(const float4*)(p + 4);
          half8 h;
          h[0] = (f16)v0.x; h[1] = (f16)v0.y; h[2] = (f16)v0.z; h[3] = (f16)v0.w;
          h[4] = (f16)v1.x; h[5] = (f16)v1.y; h[6] = (f16)v1.z; h[7] = (f16)v1.w;
          *(half8*)(Bl + slot * 8) = h;
        }
      }
    }
    __syncthreads();
    const int frow = lane & 15;
    const int fkc = (lane >> 4) * 8;
    half8 af[4], bf[4];
#pragma unroll
    for (int m = 0; m < 4; ++m)
      af[m] = *(const half8*)(Al + (wr * 64 + m * 16 + frow) * 32 + fkc);
#pragma unroll
    for (int n = 0; n < 4; ++n)
      bf[n] = *(const half8*)(Bl + (wc * 64 + n * 16 + frow) * 32 + fkc);
#pragma unroll
    for (int m = 0; m < 4; ++m)
#pragma unroll
      for (int n = 0; n < 4; ++n)
        acc[m][n] = __builtin_amdgcn_mfma_f32_16x16x32_f16(af[m], bf[n],
                                                           acc[m][n], 0, 0, 0);
  }
  const int crow = (lane >> 4) * 4;
  const int ccol = lane & 15;
#pragma unroll
  for (int m = 0; m < 4; ++m)
#pragma unroll
    for (int n = 0; n < 4; ++n)
#pragma unroll
      for (int r = 0; r < 4; ++r) {
        long row = m0 + wr * 64 + m * 16 + crow + r;
        long col = n0 + wc * 64 + n * 16 + ccol;
        if constexpr (CT)
          C[(coff + col) * ldc + row] = (f16)acc[m][n][r];
        else
          C[row * ldc + coff + col] = (f16)acc[m][n][r];
      }
}

// zero tagged buffer: 34816 u64 (yVp 32768 + s0p 2048). MUST run every launch.
__global__ void zero_ybuf(u64* ybuf) {
  ybuf[(size_t)blockIdx.x * 256 + threadIdx.x] = 0ull;
}

// 256 WGs: wg = s*8 + g. g = chain group (chains 8g..8g+7, one XCD per group),
// s = slice. s<16: Vh cols [s*32,s*32+32); s>=16: q cols [(s-16)*32 ...).
// yVp[8g][2par][8ch][256 pairs] u64 {tag, 2xf16}; s0p[8][2][8][16 qslice].
__global__ __launch_bounds__(256, 1)
void seq_kernel(const f16* __restrict__ Wt, const f16* __restrict__ GXV,
                u64* __restrict__ ybuf, float* __restrict__ out) {
  const int wg = blockIdx.x;
  const int g = wg & 7;
  const int s = wg >> 3;
  const int tid = threadIdx.x;
  const int lane = tid & 63;
  const int wid = tid >> 6;
  const int T = 512;

  __shared__ __align__(16) char wlds[32 * 1024];  // W slice [32 col][512 u] f16, XOR
  __shared__ __align__(16) char hpkb[16 * 1024];  // h [16 ch][512 u] f16, XOR; 8-15 zero
  __shared__ floatx4 yred[4][2][64];
  __shared__ float svals12[8][2];
  __shared__ float svals0[8];

  // ---- preload weight slice (rows s*32..s*32+31 of Wt) ----
  {
    const int col = tid >> 3;
    const int seg = (tid & 7) * 128;
    const unsigned key = ((unsigned)col & 7u) << 4;
    const char* src = (const char*)(Wt + (size_t)(s * 32 + col) * 512);
#pragma unroll
    for (int jj = 0; jj < 8; ++jj) {
      half8 v = *(const half8*)(src + seg + jj * 16);
      *(half8*)(wlds + col * 1024 + ((unsigned)(seg + jj * 16) ^ key)) = v;
    }
  }
  // ---- zero h (all 16 rows) ----
#pragma unroll
  for (int i = 0; i < 4; ++i)
    *(floatx4*)(hpkb + tid * 64 + i * 16) = (floatx4){0.f, 0.f, 0.f, 0.f};
  __syncthreads();

  const float scale = 0.04419417382415922f;  // 1/sqrt(512)
  const bool isV = (s < 16);
  const int ch_own = tid >> 5;             // owner: chain 0..7
  const int c0 = (tid & 31) * 16;          // owner: 16 cols
  const unsigned hkey_own = ((unsigned)ch_own & 7u) << 4;
  u64* const yVp = ybuf;
  u64* const s0p = ybuf + 32768;

  // MFMA addressing (per lane)
  const int arow = lane & 15;
  const unsigned akey = ((unsigned)arow & 7u) << 4;
  const int bcol = lane & 15;                       // nt adds 16: same key
  const unsigned bkey = ((unsigned)bcol & 7u) << 4;
  const int koffb = wid * 256 + (lane >> 4) * 16;   // bytes within 1024B row

  for (int t = 0; t < T; ++t) {
    const int par = t & 1;
    const u64 tagw = ((u64)(unsigned)(t + 1)) << 32;

    // ---- 1. hoisted global loads ----
    const f16* rowc_own = GXV + (((size_t)g * 8 + ch_own) * T + t) * 1024;
    half8 xc = *(const half8*)(rowc_own + 512 + c0);
    half8 xp;
#pragma unroll
    for (int i = 0; i < 8; ++i) xp[i] = (f16)0.f;
    if (t > 0) xp = *(const half8*)(rowc_own - 512 + c0);
    half8 gcv[4], gpv[4];
    int sch = 0, suseg = 0;
    if (wid == 1 || wid == 2) {
      sch = (wid - 1) * 4 + (lane >> 4);
      suseg = (lane & 15) * 32;
      const f16* rowg = GXV + (((size_t)g * 8 + sch) * T + t) * 1024;
#pragma unroll
      for (int w = 0; w < 4; ++w) {
        gcv[w] = *(const half8*)(rowg + suseg + w * 8);
#pragma unroll
        for (int i = 0; i < 8; ++i) gpv[w][i] = (f16)0.f;
      }
      if (t > 0)
#pragma unroll
        for (int w = 0; w < 4; ++w)
          gpv[w] = *(const half8*)(rowg - 1024 + suseg + w * 8);
    }

    // ---- 2. MFMA matvec: y[16ch][32col] slice, K=128 per wave ----
    floatx4 acc0 = (floatx4){0.f, 0.f, 0.f, 0.f};
    floatx4 acc1 = (floatx4){0.f, 0.f, 0.f, 0.f};
#pragma unroll
    for (int ks = 0; ks < 4; ++ks) {
      const unsigned ko = (unsigned)(koffb + ks * 64);
      half8 a = *(const half8*)(hpkb + arow * 1024 + (ko ^ akey));
      half8 b0 = *(const half8*)(wlds + bcol * 1024 + (ko ^ bkey));
      half8 b1 = *(const half8*)(wlds + (16 + bcol) * 1024 + (ko ^ bkey));
      acc0 = __builtin_amdgcn_mfma_f32_16x16x32_f16(a, b0, acc0, 0, 0, 0);
      acc1 = __builtin_amdgcn_mfma_f32_16x16x32_f16(a, b1, acc1, 0, 0, 0);
    }
    yred[wid][0][lane] = acc0;
    yred[wid][1][lane] = acc1;
    __syncthreads();  // (1)

    // ---- 3. wave0: finalize + publish ; waves1-2: s1/s2 ----
    if (wid == 0) {
      floatx4 yf[2];
#pragma unroll
      for (int nt = 0; nt < 2; ++nt) {
        floatx4 v = yred[0][nt][lane];
#pragma unroll
        for (int w = 1; w < 4; ++w) {
          floatx4 u = yred[w][nt][lane];
          v[0] += u[0]; v[1] += u[1]; v[2] += u[2]; v[3] += u[3];
        }
        yf[nt] = v;
      }
      if (isV) {
#pragma unroll
        for (int nt = 0; nt < 2; ++nt)
#pragma unroll
          for (int r = 0; r < 4; ++r) {
            float v = yf[nt][r];
            float pv = __shfl_xor(v, 1);
            if (lane < 32 && !(lane & 1)) {
              h2 pk; pk[0] = (f16)v; pk[1] = (f16)pv;
              unsigned lo; __builtin_memcpy(&lo, &pk, 4);
              const int ch = (lane >> 4) * 4 + r;
              const int p = s * 16 + nt * 8 + ((lane & 15) >> 1);
              __hip_atomic_store(
                  yVp + (((size_t)g * 2 + par) * 8 + ch) * 256 + p,
                  tagw | (u64)lo, __ATOMIC_RELAXED, __HIP_MEMORY_SCOPE_AGENT);
            }
          }
      } else {
        float sp[4] = {0.f, 0.f, 0.f, 0.f};
#pragma unroll
        for (int nt = 0; nt < 2; ++nt)
#pragma unroll
          for (int r = 0; r < 4; ++r) {
            const int c = (s - 16) * 32 + nt * 16 + (lane & 15);
            const int ch = (lane >> 4) * 4 + r;
            const unsigned key = ((unsigned)ch & 7u) << 4;
            f16 hv = *(const f16*)(hpkb + ch * 1024 + (((unsigned)(2 * c)) ^ key));
            sp[r] += yf[nt][r] * (float)hv;
          }
#pragma unroll
        for (int r = 0; r < 4; ++r) {
          sp[r] += __shfl_xor(sp[r], 1);
          sp[r] += __shfl_xor(sp[r], 2);
          sp[r] += __shfl_xor(sp[r], 4);
          sp[r] += __shfl_xor(sp[r], 8);
        }
        if (lane < 32 && (lane & 15) == 0) {
          const int chb = (lane >> 4) * 4;
#pragma unroll
          for (int r = 0; r < 4; ++r) {
            unsigned bits = __float_as_uint(sp[r]);
            __hip_atomic_store(
                s0p + (((size_t)g * 2 + par) * 8 + chb + r) * 16 + (s - 16),
                tagw | (u64)bits, __ATOMIC_RELAXED, __HIP_MEMORY_SCOPE_AGENT);
          }
        }
      }
    } else if (wid < 3) {
      const unsigned skey = ((unsigned)sch & 7u) << 4;
      half8 hh[4];
#pragma unroll
      for (int w = 0; w < 4; ++w)
        hh[w] = *(const half8*)(hpkb + sch * 1024 +
                                (((unsigned)(suseg * 2 + w * 16)) ^ skey));
      float s1a = 0.f, s2a = 0.f;
#pragma unroll
      for (int w = 0; w < 4; ++w)
#pragma unroll
        for (int e = 0; e < 4; ++e) {
          h2 hp; hp[0] = hh[w][2 * e]; hp[1] = hh[w][2 * e + 1];
          h2 gp_; gp_[0] = gpv[w][2 * e]; gp_[1] = gpv[w][2 * e + 1];
          h2 gc_; gc_[0] = gcv[w][2 * e]; gc_[1] = gcv[w][2 * e + 1];
          s1a = dot2f(gp_, hp, s1a);
          s2a = dot2f(gc_, hp, s2a);
        }
      s1a += __shfl_xor(s1a, 1); s2a += __shfl_xor(s2a, 1);
      s1a += __shfl_xor(s1a, 2); s2a += __shfl_xor(s2a, 2);
      s1a += __shfl_xor(s1a, 4); s2a += __shfl_xor(s2a, 4);
      s1a += __shfl_xor(s1a, 8); s2a += __shfl_xor(s2a, 8);
      if ((lane & 15) == 0) {
        svals12[sch][0] = s1a;
        svals12[sch][1] = s2a;
      }
    }

    // ---- 4. poll own 8 pair-words (+1 s0 word for tid<128) ----
    const u64* ybase =
        yVp + (((size_t)g * 2 + par) * 8 + ch_own) * 256 + (tid & 31) * 8;
    const u64* s0addr =
        s0p + (((size_t)g * 2 + par) * 8 + (tid >> 4)) * 16 + (tid & 15);
    u64 pw[8];
    u64 s0w = tagw;
    for (;;) {
      bool ok = true;
#pragma unroll
      for (int i = 0; i < 8; ++i) {
        pw[i] = __hip_atomic_load(ybase + i, __ATOMIC_RELAXED,
                                  __HIP_MEMORY_SCOPE_AGENT);
        ok = ok && (pw[i] >= tagw);
      }
      if (tid < 128) {
        s0w = __hip_atomic_load(s0addr, __ATOMIC_RELAXED,
                                __HIP_MEMORY_SCOPE_AGENT);
        ok = ok && (s0w >= tagw);
      }
      if (ok) break;
      __builtin_amdgcn_s_sleep(1);
    }

    // ---- 5. assemble s0 ----
    if (tid < 128) {
      float sp = __uint_as_float((unsigned)s0w);
      sp += __shfl_xor(sp, 1);
      sp += __shfl_xor(sp, 2);
      sp += __shfl_xor(sp, 4);
      sp += __shfl_xor(sp, 8);
      if ((lane & 15) == 0) svals0[tid >> 4] = sp;
    }
    __syncthreads();  // (2)

    // ---- 6. softmax + h update (owner: ch_own, cols c0..c0+15) ----
    {
      float s0v = svals0[ch_own] * scale;
      float s1v = svals12[ch_own][0] * scale;
      float s2v = svals12[ch_own][1] * scale;
      float mx = fmaxf(s0v, fmaxf(s1v, s2v));
      float e0 = __expf(s0v - mx), e1 = __expf(s1v - mx), e2 = __expf(s2v - mx);
      float inv = 1.f / (e0 + e1 + e2);
      float a0 = e0 * inv, a1 = e1 * inv, a2 = e2 * inv;
      half8 hna, hnb;
#pragma unroll
      for (int i = 0; i < 8; ++i) {
        unsigned lo = (unsigned)pw[i];
        h2 vh; __builtin_memcpy(&vh, &lo, 4);
        float f0 = a0 * (float)vh[0] + a1 * (float)xp[i] + a2 * (float)xc[i];
        // xc/xp half8 element j corresponds to col c0+j; pair i covers cols
        // (c0+2i, c0+2i+1) -> elements 2i, 2i+1. Recompute properly below.
        (void)f0;
      }
      // correct element mapping: pair i -> xc[2i], xc[2i+1] with i in [0,8):
      float hnf[16];
#pragma unroll
      for (int i = 0; i < 8; ++i) {
        unsigned lo = (unsigned)pw[i];
        h2 vh; __builtin_memcpy(&vh, &lo, 4);
        const int j0 = 2 * i, j1 = 2 * i + 1;
        float xpc0 = (j0 < 8) ? (float)xp[j0] : (float)xp[j0 - 8];
        (void)xpc0;
        hnf[j0] = 0.f; hnf[j1] = 0.f;  // placeholder, set below
      }
      // xc/xp cover 8 f16 = cols c0..c0+7 ONLY — need 16 cols: load both halves.
      half8 xc2 = *(const half8*)(rowc_own + 512 + c0 + 8);
      half8 xp2;
#pragma unroll
      for (int i = 0; i < 8; ++i) xp2[i] = (f16)0.f;
      if (t > 0) xp2 = *(const half8*)(rowc_own - 512 + c0 + 8);
#pragma unroll
      for (int i = 0; i < 8; ++i) {
        unsigned lo = (unsigned)pw[i];
        h2 vh; __builtin_memcpy(&vh, &lo, 4);
        const int j0 = 2 * i, j1 = 2 * i + 1;
        float xcj0 = (j0 < 8) ? (float)xc[j0] : (float)xc2[j0 - 8];
        float xcj1 = (j1 < 8) ? (float)xc[j1] : (float)xc2[j1 - 8];
        float xpj0 = (j0 < 8) ? (float)xp[j0] : (float)xp2[j0 - 8];
        float xpj1 = (j1 < 8) ? (float)xp[j1] : (float)xp2[j1 - 8];
        hnf[j0] = a0 * (float)vh[0] + a1 * xpj0 + a2 * xcj0;
        hnf[j1] = a0 * (float)vh[1] + a1 * xpj1 + a2 * xcj1;
      }
#pragma unroll
      for (int j = 0; j < 8; ++j) { hna[j] = (f16)hnf[j]; hnb[j] = (f16)hnf[j + 8]; }
      *(half8*)(hpkb + ch_own * 1024 + (((unsigned)(2 * c0)) ^ hkey_own)) = hna;
      *(half8*)(hpkb + ch_own * 1024 + (((unsigned)(2 * c0 + 16)) ^ hkey_own)) = hnb;
      if (t == T - 1 && s == 0) {
        float* ob = out + ((size_t)g * 8 + ch_own) * 512 + c0;
#pragma unroll
        for (int j = 0; j < 16; ++j) ob[j] = hnf[j];
      }
    }
    __syncthreads();  // (3)
  }
}

extern "C" void kernel_launch(void* const* d_in, const int* in_sizes, int n_in,
                              void* d_out, int out_size, void* d_ws,
                              size_t ws_size, hipStream_t stream) {
  const float* x = (const float*)d_in[0];     // [64][512][512]
  const float* Wq = (const float*)d_in[1];
  const float* Wk = (const float*)d_in[2];
  const float* Wv = (const float*)d_in[3];
  const float* Wrec = (const float*)d_in[4];
  float* out = (float*)d_out;                 // [64][512]

  char* ws = (char*)d_ws;
  f16* GXV = (f16*)ws;                        // [32768][1024] f16 = 64 MiB
  f16* Wt = (f16*)(ws + 67108864);            // [1024][512] f16 = 1 MiB
  f16* Wrk = (f16*)(ws + 68157440);           // 512 KiB
  f16* Wrq = (f16*)(ws + 68681728);           // 512 KiB (ybuf overlays after use)
  f16* WgT = (f16*)(ws + 69206016);           // 512 KiB
  u64* ybuf = (u64*)(ws + 68681728);          // 34816 u64 = 272 KiB

  // ---- weight combinations ----
  gemm128<AM_F32, BM_NN_F32, 0><<<16, 256, 0, stream>>>(Wrec, Wk, Wrk, 512, 512, 512, 0, 4);
  gemm128<AM_F32, BM_NN_F32, 0><<<16, 256, 0, stream>>>(Wrec, Wq, Wrq, 512, 512, 512, 0, 4);
  // Wt rows 0..511  = Wrv^T
  gemm128<AM_F32, BM_NN_F32, 1><<<16, 256, 0, stream>>>(Wrec, Wv, Wt, 512, 512, 512, 0, 4);
  // Wt rows 512..1023 = Wkq^T  (Wkq = Wrk@Wrq^T)
  gemm128<AM_F16, BM_BT_F16, 1><<<16, 256, 0, stream>>>(Wrk, Wrq, Wt, 512, 0, 512, 512, 4);
  // WgT = Wrk@Wq^T
  gemm128<AM_F16, BM_BT_F32, 0><<<16, 256, 0, stream>>>(Wrk, Wq, WgT, 512, 0, 512, 0, 4);
  // G and XV for all (b,t)
  gemm128<AM_F32, BM_BT_F16, 0><<<1024, 256, 0, stream>>>(x, WgT, GXV, 512, 0, 1024, 0, 4);
  gemm128<AM_F32, BM_NN_F32, 0><<<1024, 256, 0, stream>>>(x, Wv, GXV, 512, 512, 1024, 512, 4);

  // zero tagged buffer (after gemms that used the overlaid region)
  zero_ybuf<<<136, 256, 0, stream>>>(ybuf);

  // ---- sequential recurrence: cooperative, 256 WGs = 1 per CU ----
  const f16* WtC = Wt; const f16* GXVC = GXV;
  void* args[] = {(void*)&WtC, (void*)&GXVC, (void*)&ybuf, (void*)&out};
  dim3 grid(256), block(256);
  if (hipLaunchCooperativeKernel((const void*)seq_kernel, grid, block, args, 0,
                                 stream) != hipSuccess) {
    seq_kernel<<<grid, block, 0, stream>>>(WtC, GXVC, ybuf, out);
  }
}

// Round 8
// 2155.207 us; speedup vs baseline: 1.5477x; 1.5477x over previous
//
#include <hip/hip_runtime.h>

// ---------------------------------------------------------------------------
// Self_RNN forward, MI355X.
//   Wrv = Wrec@Wv ; Wrk = Wrec@Wk ; Wrq = Wrec@Wq ; Wkq = Wrk@Wrq^T
//   WgT = Wrk@Wq^T ; G[b,t] = x[b,t]@WgT^T ; XV[b,t] = x[b,t]@Wv
//   per step: y = h @ [Wrv | Wkq]  -> Vh = y[0:512], q = y[512:1024]
//             s0=(q.h)sc, s1=(h.G[t-1])sc, s2=(h.G[t])sc ; a=softmax(s)
//             h' = a0*Vh + a1*XV[t-1] + a2*XV[t]
// Sequential phase: 256 coop WGs = 16 groups (4 chains) x 16 slices (64 cols)
// = R6's proven comm shape. Matvec via MFMA 16x16x32 f16 (chains = A rows
// 0-3, rows 4-15 zero; B = W[col][k] LDS, both XOR-swizzled), K split over
// 4 waves + 4KB LDS reduce. Publish stays 256-thread-parallel (R7 lesson).
// Sync = tagged u64; Vh as {tag, 2xf16} pairs; q-slices publish 1 s0-partial
// per chain. s1/s2 in MFMA shadow; s0 assembled in-register; 2 barriers/step.
// ---------------------------------------------------------------------------

typedef _Float16 f16;
typedef _Float16 half8 __attribute__((ext_vector_type(8)));
typedef _Float16 h2 __attribute__((ext_vector_type(2)));
typedef float floatx4 __attribute__((ext_vector_type(4)));
typedef unsigned long long u64;

#define AM_F32 0
#define AM_F16 1
#define BM_NN_F32 0   // B  is [K][N] f32 (transpose-staged)
#define BM_BT_F16 1   // Bt is [N][K] f16
#define BM_BT_F32 2   // Bt is [N][K] f32

#if defined(__has_builtin)
#if __has_builtin(__builtin_amdgcn_fdot2)
#define HAS_FDOT2 1
#endif
#endif

__device__ inline float dot2f(h2 a, h2 b, float c) {
#ifdef HAS_FDOT2
  return __builtin_amdgcn_fdot2(a, b, c, false);
#else
  return c + (float)a[0] * (float)b[0] + (float)a[1] * (float)b[1];
#endif
}

// C[M,N] = A[M,K] @ B ; 128x128 tile, BK=32, 4 waves, MFMA f16.
// CT=0: C[row*ldc + coff + col]   CT=1: C[(coff+col)*ldc + row]
template<int AMODE, int BMODE, int CT>
__global__ __launch_bounds__(256)
void gemm128(const void* __restrict__ Ap, const void* __restrict__ Bp,
             f16* __restrict__ C, int K, int ldbnn, long ldc, long coff,
             int ntiles) {
  __shared__ f16 Al[128 * 32];
  __shared__ f16 Bl[128 * 32];
  const int tid = threadIdx.x;
  const int lane = tid & 63;
  const int wid = tid >> 6;
  const int wr = wid >> 1, wc = wid & 1;
  const int mt = blockIdx.x / ntiles, nt = blockIdx.x % ntiles;
  const long m0 = (long)mt * 128, n0 = (long)nt * 128;

  floatx4 acc[4][4];
#pragma unroll
  for (int m = 0; m < 4; ++m)
#pragma unroll
    for (int n = 0; n < 4; ++n) acc[m][n] = (floatx4){0.f, 0.f, 0.f, 0.f};

  for (int k0 = 0; k0 < K; k0 += 32) {
    __syncthreads();
#pragma unroll
    for (int i = 0; i < 2; ++i) {
      const int slot = i * 256 + tid;
      const int row = slot >> 2;
      const int kc = (slot & 3) * 8;
      if constexpr (AMODE == AM_F16) {
        const f16* Ag = (const f16*)Ap;
        half8 v = *(const half8*)(Ag + (m0 + row) * (long)K + k0 + kc);
        *(half8*)(Al + slot * 8) = v;
      } else {
        const float* Ag = (const float*)Ap;
        const float* p = Ag + (m0 + row) * (long)K + k0 + kc;
        float4 v0 = *(const float4*)(p);
        float4 v1 = *(const float4*)(p + 4);
        half8 h;
        h[0] = (f16)v0.x; h[1] = (f16)v0.y; h[2] = (f16)v0.z; h[3] = (f16)v0.w;
        h[4] = (f16)v1.x; h[5] = (f16)v1.y; h[6] = (f16)v1.z; h[7] = (f16)v1.w;
        *(half8*)(Al + slot * 8) = h;
      }
    }
    if constexpr (BMODE == BM_NN_F32) {
      const float* Bg = (const float*)Bp;
      const int nn = tid & 127;
      const int kh = (tid >> 7) * 16;
#pragma unroll
      for (int j = 0; j < 16; j += 2) {
        float b0 = Bg[(long)(k0 + kh + j) * ldbnn + n0 + nn];
        float b1 = Bg[(long)(k0 + kh + j + 1) * ldbnn + n0 + nn];
        h2 hv; hv[0] = (f16)b0; hv[1] = (f16)b1;
        *(h2*)(Bl + nn * 32 + kh + j) = hv;
      }
    } else {
#pragma unroll
      for (int i = 0; i < 2; ++i) {
        const int slot = i * 256 + tid;
        const int row = slot >> 2;
        const int kc = (slot & 3) * 8;
        if constexpr (BMODE == BM_BT_F16) {
          const f16* Bg = (const f16*)Bp;
          half8 v = *(const half8*)(Bg + (n0 + row) * (long)K + k0 + kc);
          *(half8*)(Bl + slot * 8) = v;
        } else {
          const float* Bg = (const float*)Bp;
          const float* p = Bg + (n0 + row) * (long)K + k0 + kc;
          float4 v0 = *(const float4*)(p);
          float4 v1 = *(const float4*)(p + 4);
          half8 h;
          h[0] = (f16)v0.x; h[1] = (f16)v0.y; h[2] = (f16)v0.z; h[3] = (f16)v0.w;
          h[4] = (f16)v1.x; h[5] = (f16)v1.y; h[6] = (f16)v1.z; h[7] = (f16)v1.w;
          *(half8*)(Bl + slot * 8) = h;
        }
      }
    }
    __syncthreads();
    const int frow = lane & 15;
    const int fkc = (lane >> 4) * 8;
    half8 af[4], bf[4];
#pragma unroll
    for (int m = 0; m < 4; ++m)
      af[m] = *(const half8*)(Al + (wr * 64 + m * 16 + frow) * 32 + fkc);
#pragma unroll
    for (int n = 0; n < 4; ++n)
      bf[n] = *(const half8*)(Bl + (wc * 64 + n * 16 + frow) * 32 + fkc);
#pragma unroll
    for (int m = 0; m < 4; ++m)
#pragma unroll
      for (int n = 0; n < 4; ++n)
        acc[m][n] = __builtin_amdgcn_mfma_f32_16x16x32_f16(af[m], bf[n],
                                                           acc[m][n], 0, 0, 0);
  }
  const int crow = (lane >> 4) * 4;
  const int ccol = lane & 15;
#pragma unroll
  for (int m = 0; m < 4; ++m)
#pragma unroll
    for (int n = 0; n < 4; ++n)
#pragma unroll
      for (int r = 0; r < 4; ++r) {
        long row = m0 + wr * 64 + m * 16 + crow + r;
        long col = n0 + wc * 64 + n * 16 + ccol;
        if constexpr (CT)
          C[(coff + col) * ldc + row] = (f16)acc[m][n][r];
        else
          C[row * ldc + coff + col] = (f16)acc[m][n][r];
      }
}

// zero tagged buffer: 33792 u64 (yVp 32768 + s0p 1024). MUST run every launch.
__global__ void zero_ybuf(u64* ybuf) {
  ybuf[(size_t)blockIdx.x * 256 + threadIdx.x] = 0ull;
}

// 256 WGs: wg = s*16 + grp. grp = chain group (chains 4grp..4grp+3),
// s = slice: s<8 -> Vh cols [s*64,s*64+64); s>=8 -> q cols [(s-8)*64 ...).
// yVp[16grp][2par][4ch][256 pairs] u64 {tag, 2xf16}; s0p[16][2][4][8 qslice].
__global__ __launch_bounds__(256, 1)
void seq_kernel(const f16* __restrict__ Wt, const f16* __restrict__ GXV,
                u64* __restrict__ ybuf, float* __restrict__ out) {
  const int wg = blockIdx.x;
  const int grp = wg & 15;
  const int s = wg >> 4;
  const int tid = threadIdx.x;
  const int lane = tid & 63;
  const int wid = tid >> 6;
  const int T = 512;

  __shared__ __align__(16) char wlds[64 * 1024];  // W slice [64col][512k] f16 XOR
  __shared__ __align__(16) char hpkb[16 * 1024];  // h [16r][512u] f16 XOR; r4-15=0
  __shared__ floatx4 yred[4][4][16];              // [wave][ntile][lane0-15]
  __shared__ float swred[4][8];

  // ---- preload weight slice (rows s*64 .. s*64+63 of Wt) ----
  {
    const int col = tid >> 2;
    const int seg = (tid & 3) * 256;
    const unsigned key = ((unsigned)col & 7u) << 4;
    const char* src = (const char*)(Wt + (size_t)(s * 64 + col) * 512);
#pragma unroll
    for (int k = 0; k < 16; ++k) {
      half8 v = *(const half8*)(src + seg + k * 16);
      *(half8*)(wlds + col * 1024 + ((unsigned)(seg + k * 16) ^ key)) = v;
    }
  }
  // ---- zero h (all 16 rows; rows 4-15 stay zero forever) ----
#pragma unroll
  for (int i = 0; i < 4; ++i)
    *(floatx4*)(hpkb + tid * 64 + i * 16) = (floatx4){0.f, 0.f, 0.f, 0.f};
  __syncthreads();

  const float scale = 0.04419417382415922f;  // 1/sqrt(512)
  const bool isV = (s < 8);
  const int ch = tid >> 6;          // owner chain == wave id
  const int lc = tid & 63;
  const int cb = lc * 8;            // owner col base (8 cols)
  const unsigned hkey = ((unsigned)ch) << 4;
  u64* const yVp = ybuf;
  u64* const s0p = ybuf + 32768;

  // MFMA fragment addressing (per lane): A row / B col = lane&15
  const int arow = lane & 15;
  const unsigned abkey = ((unsigned)(arow & 7)) << 4;
  const int kbase = wid * 256 + (lane >> 4) * 16;  // byte off of k in 1024B row

  for (int t = 0; t < T; ++t) {
    const int par = t & 1;
    const u64 tagw = ((u64)(unsigned)(t + 1)) << 32;

    // ---- A. hoisted global loads (latency hidden under MFMA + s1/s2) ----
    const f16* rowc = GXV + (((size_t)grp * 4 + ch) * T + t) * 1024;
    half8 xc = *(const half8*)(rowc + 512 + cb);
    half8 xp;
#pragma unroll
    for (int i = 0; i < 8; ++i) xp[i] = (f16)0.f;
    if (t > 0) xp = *(const half8*)(rowc - 512 + cb);
    h2 gcv[4], gpv[4];
#pragma unroll
    for (int c4 = 0; c4 < 4; ++c4) {
      const f16* rg = GXV + (((size_t)grp * 4 + c4) * T + t) * 1024;
      gcv[c4] = *(const h2*)(rg + 2 * tid);
      h2 z; z[0] = (f16)0.f; z[1] = (f16)0.f;
      gpv[c4] = z;
      if (t > 0) gpv[c4] = *(const h2*)(rg - 1024 + 2 * tid);
    }

    // ---- B. MFMA matvec: y[4ch][64col], this wave's K-quarter ----
    floatx4 acc[4];
#pragma unroll
    for (int nt = 0; nt < 4; ++nt) acc[nt] = (floatx4){0.f, 0.f, 0.f, 0.f};
#pragma unroll
    for (int i = 0; i < 4; ++i) {
      const unsigned ko = (unsigned)(kbase + i * 64);
      half8 av = *(const half8*)(hpkb + arow * 1024 + (ko ^ abkey));
#pragma unroll
      for (int nt = 0; nt < 4; ++nt) {
        half8 bv = *(const half8*)(wlds + (nt * 16 + arow) * 1024 + (ko ^ abkey));
        acc[nt] = __builtin_amdgcn_mfma_f32_16x16x32_f16(av, bv, acc[nt], 0, 0, 0);
      }
    }

    // ---- C. s1/s2 partials (VALU, overlaps MFMA pipe) ----
    {
      float pr[8];
#pragma unroll
      for (int c4 = 0; c4 < 4; ++c4) {
        h2 hv = *(const h2*)(hpkb + c4 * 1024 +
                             (((unsigned)(4 * tid)) ^ (((unsigned)c4) << 4)));
        pr[2 * c4] = dot2f(gpv[c4], hv, 0.f);
        pr[2 * c4 + 1] = dot2f(gcv[c4], hv, 0.f);
      }
#pragma unroll
      for (int off = 32; off > 0; off >>= 1)
#pragma unroll
        for (int i = 0; i < 8; ++i) pr[i] += __shfl_down(pr[i], off);
      if (lane == 0) {
#pragma unroll
        for (int i = 0; i < 8; ++i) swred[wid][i] = pr[i];
      }
    }

    // ---- D. stash MFMA result (rows 0-3 live in lanes 0-15) ----
    if (lane < 16) {
#pragma unroll
      for (int nt = 0; nt < 4; ++nt) yred[wid][nt][lane] = acc[nt];
    }
    __syncthreads();  // (1): yred + swred visible; h reads done before writes

    // ---- E. reduce over 4 waves + publish (all threads in parallel) ----
    {
      const int nt = lc >> 4, l15 = lc & 15;
      float y = 0.f;
#pragma unroll
      for (int w = 0; w < 4; ++w)
        y += ((const float*)&yred[w][nt][l15])[ch];
      if (isV) {
        float yp = __shfl_xor(y, 1);
        if (!(lane & 1)) {
          h2 pk; pk[0] = (f16)y; pk[1] = (f16)yp;
          unsigned lo; __builtin_memcpy(&lo, &pk, 4);
          __hip_atomic_store(
              yVp + (((size_t)grp * 2 + par) * 4 + ch) * 256 + s * 32 + (lc >> 1),
              tagw | (u64)lo, __ATOMIC_RELAXED, __HIP_MEMORY_SCOPE_AGENT);
        }
      } else {
        const int u = (s - 8) * 64 + lc;
        f16 hu = *(const f16*)(hpkb + ch * 1024 + (((unsigned)(2 * u)) ^ hkey));
        float p = y * (float)hu;
#pragma unroll
        for (int off = 32; off > 0; off >>= 1) p += __shfl_down(p, off);
        if (lane == 0)
          __hip_atomic_store(
              s0p + (((size_t)grp * 2 + par) * 4 + ch) * 8 + (s - 8),
              tagw | (u64)__float_as_uint(p), __ATOMIC_RELAXED,
              __HIP_MEMORY_SCOPE_AGENT);
      }
    }

    // ---- F. poll: 4 Vh pair-words (own 8 cols) + 1 s0 partial ----
    const u64* vb = yVp + (((size_t)grp * 2 + par) * 4 + ch) * 256 + lc * 4;
    const u64* sb = s0p + (((size_t)grp * 2 + par) * 4 + ch) * 8 + (tid & 7);
    u64 v0, v1, v2, v3, sw;
    for (;;) {
      v0 = __hip_atomic_load(vb + 0, __ATOMIC_RELAXED, __HIP_MEMORY_SCOPE_AGENT);
      v1 = __hip_atomic_load(vb + 1, __ATOMIC_RELAXED, __HIP_MEMORY_SCOPE_AGENT);
      v2 = __hip_atomic_load(vb + 2, __ATOMIC_RELAXED, __HIP_MEMORY_SCOPE_AGENT);
      v3 = __hip_atomic_load(vb + 3, __ATOMIC_RELAXED, __HIP_MEMORY_SCOPE_AGENT);
      sw = __hip_atomic_load(sb, __ATOMIC_RELAXED, __HIP_MEMORY_SCOPE_AGENT);
      if (v0 >= tagw && v1 >= tagw && v2 >= tagw && v3 >= tagw && sw >= tagw)
        break;
      __builtin_amdgcn_s_sleep(1);
    }

    // ---- G. s0 in-register (8-lane group) + softmax ----
    float sp = __uint_as_float((unsigned)sw);
    sp += __shfl_xor(sp, 1);
    sp += __shfl_xor(sp, 2);
    sp += __shfl_xor(sp, 4);
    const float sv0 = sp * scale;
    const float sv1 = (swred[0][2 * ch] + swred[1][2 * ch] + swred[2][2 * ch] +
                       swred[3][2 * ch]) * scale;
    const float sv2 = (swred[0][2 * ch + 1] + swred[1][2 * ch + 1] +
                       swred[2][2 * ch + 1] + swred[3][2 * ch + 1]) * scale;
    const float mx = fmaxf(sv0, fmaxf(sv1, sv2));
    const float e0 = __expf(sv0 - mx), e1 = __expf(sv1 - mx), e2 = __expf(sv2 - mx);
    const float inv = 1.f / (e0 + e1 + e2);
    const float a0 = e0 * inv, a1 = e1 * inv, a2 = e2 * inv;

    // ---- H. h update for own 8 cols ----
    {
      float hnf[8];
      u64 vw[4] = {v0, v1, v2, v3};
#pragma unroll
      for (int i = 0; i < 4; ++i) {
        unsigned lo = (unsigned)vw[i];
        h2 vh; __builtin_memcpy(&vh, &lo, 4);
        hnf[2 * i] = a0 * (float)vh[0] + a1 * (float)xp[2 * i] + a2 * (float)xc[2 * i];
        hnf[2 * i + 1] = a0 * (float)vh[1] + a1 * (float)xp[2 * i + 1] +
                         a2 * (float)xc[2 * i + 1];
      }
      half8 hn;
#pragma unroll
      for (int j = 0; j < 8; ++j) hn[j] = (f16)hnf[j];
      *(half8*)(hpkb + ch * 1024 + (((unsigned)(2 * cb)) ^ hkey)) = hn;
      if (t == T - 1 && s == 0) {
        float* ob = out + ((size_t)grp * 4 + ch) * 512 + cb;
#pragma unroll
        for (int j = 0; j < 8; ++j) ob[j] = hnf[j];
      }
    }
    __syncthreads();  // (2): h writes visible for next step's MFMA/s1s2
  }
}

extern "C" void kernel_launch(void* const* d_in, const int* in_sizes, int n_in,
                              void* d_out, int out_size, void* d_ws,
                              size_t ws_size, hipStream_t stream) {
  const float* x = (const float*)d_in[0];     // [64][512][512]
  const float* Wq = (const float*)d_in[1];
  const float* Wk = (const float*)d_in[2];
  const float* Wv = (const float*)d_in[3];
  const float* Wrec = (const float*)d_in[4];
  float* out = (float*)d_out;                 // [64][512]

  char* ws = (char*)d_ws;
  f16* GXV = (f16*)ws;                        // [32768][1024] f16 = 64 MiB
  f16* Wt = (f16*)(ws + 67108864);            // [1024][512] f16 = 1 MiB
  f16* Wrk = (f16*)(ws + 68157440);           // 512 KiB
  f16* Wrq = (f16*)(ws + 68681728);           // 512 KiB (ybuf overlays after use)
  f16* WgT = (f16*)(ws + 69206016);           // 512 KiB
  u64* ybuf = (u64*)(ws + 68681728);          // 33792 u64 = 264 KiB

  // ---- weight combinations ----
  gemm128<AM_F32, BM_NN_F32, 0><<<16, 256, 0, stream>>>(Wrec, Wk, Wrk, 512, 512, 512, 0, 4);
  gemm128<AM_F32, BM_NN_F32, 0><<<16, 256, 0, stream>>>(Wrec, Wq, Wrq, 512, 512, 512, 0, 4);
  // Wt rows 0..511  = Wrv^T
  gemm128<AM_F32, BM_NN_F32, 1><<<16, 256, 0, stream>>>(Wrec, Wv, Wt, 512, 512, 512, 0, 4);
  // Wt rows 512..1023 = Wkq^T  (Wkq = Wrk@Wrq^T)
  gemm128<AM_F16, BM_BT_F16, 1><<<16, 256, 0, stream>>>(Wrk, Wrq, Wt, 512, 0, 512, 512, 4);
  // WgT = Wrk@Wq^T
  gemm128<AM_F16, BM_BT_F32, 0><<<16, 256, 0, stream>>>(Wrk, Wq, WgT, 512, 0, 512, 0, 4);
  // G and XV for all (b,t)
  gemm128<AM_F32, BM_BT_F16, 0><<<1024, 256, 0, stream>>>(x, WgT, GXV, 512, 0, 1024, 0, 4);
  gemm128<AM_F32, BM_NN_F32, 0><<<1024, 256, 0, stream>>>(x, Wv, GXV, 512, 512, 1024, 512, 4);

  // zero tagged buffer (after gemms that used the overlaid region)
  zero_ybuf<<<132, 256, 0, stream>>>(ybuf);

  // ---- sequential recurrence: cooperative, 256 WGs = 1 per CU ----
  const f16* WtC = Wt; const f16* GXVC = GXV;
  void* args[] = {(void*)&WtC, (void*)&GXVC, (void*)&ybuf, (void*)&out};
  dim3 grid(256), block(256);
  if (hipLaunchCooperativeKernel((const void*)seq_kernel, grid, block, args, 0,
                                 stream) != hipSuccess) {
    seq_kernel<<<grid, block, 0, stream>>>(WtC, GXVC, ybuf, out);
  }
}

// Round 10
// 1956.731 us; speedup vs baseline: 1.7047x; 1.1014x over previous
//
#include <hip/hip_runtime.h>

// ---------------------------------------------------------------------------
// Self_RNN forward, MI355X.
//   Wrv = Wrec@Wv ; Wrk = Wrec@Wk ; Wrq = Wrec@Wq ; Wkq = Wrk@Wrq^T
//   WgT = Wrk@Wq^T ; G[b,t] = x[b,t]@WgT^T ; XV[b,t] = x[b,t]@Wv
//   per step: y = h @ [Wrv | Wkq]  -> Vh = y[0:512], q = y[512:1024]
//             s0=(q.h)sc, s1=(h.G[t-1])sc, s2=(h.G[t])sc ; a=softmax(s)
//             h' = a0*Vh + a1*XV[t-1] + a2*XV[t]
// Sequential phase: 256 coop WGs = 16 groups (4 chains) x 16 slices (64 cols).
// Transport: PROVEN agent-scope HIP atomics, tagged u64 {tag=t+1, payload}.
// Matvec via MFMA 16x16x32 f16; yred stashed [w][col][ch] so the cross-wave
// reduce reads are consecutive (zero bank conflicts — R8's regression fix).
// Vh published as {tag, 2xf16}; s0 polled by 32 threads only (contention fix).
// 3 barriers/step (R6's measured-faster pattern).
// ---------------------------------------------------------------------------

typedef _Float16 f16;
typedef _Float16 half8 __attribute__((ext_vector_type(8)));
typedef _Float16 h2 __attribute__((ext_vector_type(2)));
typedef float floatx4 __attribute__((ext_vector_type(4)));
typedef unsigned long long u64;

#define AM_F32 0
#define AM_F16 1
#define BM_NN_F32 0   // B  is [K][N] f32 (transpose-staged)
#define BM_BT_F16 1   // Bt is [N][K] f16
#define BM_BT_F32 2   // Bt is [N][K] f32

#if defined(__has_builtin)
#if __has_builtin(__builtin_amdgcn_fdot2)
#define HAS_FDOT2 1
#endif
#endif

__device__ inline float dot2f(h2 a, h2 b, float c) {
#ifdef HAS_FDOT2
  return __builtin_amdgcn_fdot2(a, b, c, false);
#else
  return c + (float)a[0] * (float)b[0] + (float)a[1] * (float)b[1];
#endif
}

// C[M,N] = A[M,K] @ B ; 128x128 tile, BK=32, 4 waves, MFMA f16.
// CT=0: C[row*ldc + coff + col]   CT=1: C[(coff+col)*ldc + row]
template<int AMODE, int BMODE, int CT>
__global__ __launch_bounds__(256)
void gemm128(const void* __restrict__ Ap, const void* __restrict__ Bp,
             f16* __restrict__ C, int K, int ldbnn, long ldc, long coff,
             int ntiles) {
  __shared__ f16 Al[128 * 32];
  __shared__ f16 Bl[128 * 32];
  const int tid = threadIdx.x;
  const int lane = tid & 63;
  const int wid = tid >> 6;
  const int wr = wid >> 1, wc = wid & 1;
  const int mt = blockIdx.x / ntiles, nt = blockIdx.x % ntiles;
  const long m0 = (long)mt * 128, n0 = (long)nt * 128;

  floatx4 acc[4][4];
#pragma unroll
  for (int m = 0; m < 4; ++m)
#pragma unroll
    for (int n = 0; n < 4; ++n) acc[m][n] = (floatx4){0.f, 0.f, 0.f, 0.f};

  for (int k0 = 0; k0 < K; k0 += 32) {
    __syncthreads();
#pragma unroll
    for (int i = 0; i < 2; ++i) {
      const int slot = i * 256 + tid;
      const int row = slot >> 2;
      const int kc = (slot & 3) * 8;
      if constexpr (AMODE == AM_F16) {
        const f16* Ag = (const f16*)Ap;
        half8 v = *(const half8*)(Ag + (m0 + row) * (long)K + k0 + kc);
        *(half8*)(Al + slot * 8) = v;
      } else {
        const float* Ag = (const float*)Ap;
        const float* p = Ag + (m0 + row) * (long)K + k0 + kc;
        float4 v0 = *(const float4*)(p);
        float4 v1 = *(const float4*)(p + 4);
        half8 h;
        h[0] = (f16)v0.x; h[1] = (f16)v0.y; h[2] = (f16)v0.z; h[3] = (f16)v0.w;
        h[4] = (f16)v1.x; h[5] = (f16)v1.y; h[6] = (f16)v1.z; h[7] = (f16)v1.w;
        *(half8*)(Al + slot * 8) = h;
      }
    }
    if constexpr (BMODE == BM_NN_F32) {
      const float* Bg = (const float*)Bp;
      const int nn = tid & 127;
      const int kh = (tid >> 7) * 16;
#pragma unroll
      for (int j = 0; j < 16; j += 2) {
        float b0 = Bg[(long)(k0 + kh + j) * ldbnn + n0 + nn];
        float b1 = Bg[(long)(k0 + kh + j + 1) * ldbnn + n0 + nn];
        h2 hv; hv[0] = (f16)b0; hv[1] = (f16)b1;
        *(h2*)(Bl + nn * 32 + kh + j) = hv;
      }
    } else {
#pragma unroll
      for (int i = 0; i < 2; ++i) {
        const int slot = i * 256 + tid;
        const int row = slot >> 2;
        const int kc = (slot & 3) * 8;
        if constexpr (BMODE == BM_BT_F16) {
          const f16* Bg = (const f16*)Bp;
          half8 v = *(const half8*)(Bg + (n0 + row) * (long)K + k0 + kc);
          *(half8*)(Bl + slot * 8) = v;
        } else {
          const float* Bg = (const float*)Bp;
          const float* p = Bg + (n0 + row) * (long)K + k0 + kc;
          float4 v0 = *(const float4*)(p);
          float4 v1 = *(const float4*)(p + 4);
          half8 h;
          h[0] = (f16)v0.x; h[1] = (f16)v0.y; h[2] = (f16)v0.z; h[3] = (f16)v0.w;
          h[4] = (f16)v1.x; h[5] = (f16)v1.y; h[6] = (f16)v1.z; h[7] = (f16)v1.w;
          *(half8*)(Bl + slot * 8) = h;
        }
      }
    }
    __syncthreads();
    const int frow = lane & 15;
    const int fkc = (lane >> 4) * 8;
    half8 af[4], bf[4];
#pragma unroll
    for (int m = 0; m < 4; ++m)
      af[m] = *(const half8*)(Al + (wr * 64 + m * 16 + frow) * 32 + fkc);
#pragma unroll
    for (int n = 0; n < 4; ++n)
      bf[n] = *(const half8*)(Bl + (wc * 64 + n * 16 + frow) * 32 + fkc);
#pragma unroll
    for (int m = 0; m < 4; ++m)
#pragma unroll
      for (int n = 0; n < 4; ++n)
        acc[m][n] = __builtin_amdgcn_mfma_f32_16x16x32_f16(af[m], bf[n],
                                                           acc[m][n], 0, 0, 0);
  }
  const int crow = (lane >> 4) * 4;
  const int ccol = lane & 15;
#pragma unroll
  for (int m = 0; m < 4; ++m)
#pragma unroll
    for (int n = 0; n < 4; ++n)
#pragma unroll
      for (int r = 0; r < 4; ++r) {
        long row = m0 + wr * 64 + m * 16 + crow + r;
        long col = n0 + wc * 64 + n * 16 + ccol;
        if constexpr (CT)
          C[(coff + col) * ldc + row] = (f16)acc[m][n][r];
        else
          C[row * ldc + coff + col] = (f16)acc[m][n][r];
      }
}

// zero tagged buffer: 33792 u64 (yVp 32768 + s0p 1024). MUST run every launch.
__global__ void zero_ybuf(u64* ybuf) {
  ybuf[(size_t)blockIdx.x * 256 + threadIdx.x] = 0ull;
}

// 256 WGs: wg = s*16 + grp. grp = chain group (chains 4grp..4grp+3),
// s = slice: s<8 -> Vh cols [s*64,s*64+64); s>=8 -> q cols [(s-8)*64 ...).
// yVp[16grp][2par][4ch][256 pairs] u64 {tag, 2xf16}; s0p[16][2][4][8 qslice].
__global__ __launch_bounds__(256, 1)
void seq_kernel(const f16* __restrict__ Wt, const f16* __restrict__ GXV,
                u64* __restrict__ ybuf, float* __restrict__ out) {
  const int wg = blockIdx.x;
  const int grp = wg & 15;
  const int s = wg >> 4;
  const int tid = threadIdx.x;
  const int lane = tid & 63;
  const int wid = tid >> 6;
  const int T = 512;

  __shared__ __align__(16) char wlds[64 * 1024];  // W slice [64col][512k] f16 XOR
  __shared__ __align__(16) char hpkb[16 * 1024];  // h [16r][512u] f16 XOR; r4-15=0
  __shared__ float yredf[4 * 256];                // [w][col*4+ch] (consecutive!)
  __shared__ float swred[4][8];
  __shared__ float aa[4][4];                      // a0,a1,a2 per chain

  // ---- preload weight slice (rows s*64 .. s*64+63 of Wt) ----
  {
    const int col = tid >> 2;
    const int seg = (tid & 3) * 256;
    const unsigned key = ((unsigned)col & 7u) << 4;
    const char* src = (const char*)(Wt + (size_t)(s * 64 + col) * 512);
#pragma unroll
    for (int k = 0; k < 16; ++k) {
      half8 v = *(const half8*)(src + seg + k * 16);
      *(half8*)(wlds + col * 1024 + ((unsigned)(seg + k * 16) ^ key)) = v;
    }
  }
  // ---- zero h (all 16 rows; rows 4-15 stay zero forever) ----
#pragma unroll
  for (int i = 0; i < 4; ++i)
    *(floatx4*)(hpkb + tid * 64 + i * 16) = (floatx4){0.f, 0.f, 0.f, 0.f};
  __syncthreads();

  const float scale = 0.04419417382415922f;  // 1/sqrt(512)
  const bool isV = (s < 8);
  u64* const yVp = ybuf;
  u64* const s0p = ybuf + 32768;

  // MFMA fragment addressing (per lane): A row / B col = lane&15
  const int arow = lane & 15;
  const unsigned abkey = ((unsigned)(arow & 7)) << 4;
  const int kbase = wid * 256 + (lane >> 4) * 16;  // byte off of k in 1024B row

  for (int t = 0; t < T; ++t) {
    const int par = t & 1;
    const u64 tagw = ((u64)(unsigned)(t + 1)) << 32;

    // ---- A. hoisted global loads (own u-pair = {2tid, 2tid+1} per chain) ----
    h2 xc4[4], xp4[4], gcv[4], gpv[4];
#pragma unroll
    for (int c4 = 0; c4 < 4; ++c4) {
      const f16* rowc = GXV + (((size_t)grp * 4 + c4) * T + t) * 1024;
      gcv[c4] = *(const h2*)(rowc + 2 * tid);
      xc4[c4] = *(const h2*)(rowc + 512 + 2 * tid);
      h2 z; z[0] = (f16)0.f; z[1] = (f16)0.f;
      gpv[c4] = z; xp4[c4] = z;
      if (t > 0) {
        gpv[c4] = *(const h2*)(rowc - 1024 + 2 * tid);
        xp4[c4] = *(const h2*)(rowc - 512 + 2 * tid);
      }
    }

    // ---- B. MFMA matvec: y[4ch][64col], this wave's K-quarter ----
    {
      floatx4 acc[4];
#pragma unroll
      for (int nt = 0; nt < 4; ++nt) acc[nt] = (floatx4){0.f, 0.f, 0.f, 0.f};
#pragma unroll
      for (int i = 0; i < 4; ++i) {
        const unsigned ko = (unsigned)(kbase + i * 64);
        half8 av = *(const half8*)(hpkb + arow * 1024 + (ko ^ abkey));
#pragma unroll
        for (int nt = 0; nt < 4; ++nt) {
          half8 bv = *(const half8*)(wlds + (nt * 16 + arow) * 1024 + (ko ^ abkey));
          acc[nt] = __builtin_amdgcn_mfma_f32_16x16x32_f16(av, bv, acc[nt], 0, 0, 0);
        }
      }
      // stash [w][col][ch]: lane<16 holds chains 0-3 (regs) for col nt*16+lane
      if (lane < 16) {
#pragma unroll
        for (int nt = 0; nt < 4; ++nt)
          *(floatx4*)&yredf[wid * 256 + (nt * 16 + lane) * 4] = acc[nt];
      }
    }

    // ---- C. s1/s2 partials (VALU) ----
    {
      float pr[8];
#pragma unroll
      for (int c4 = 0; c4 < 4; ++c4) {
        h2 hv = *(const h2*)(hpkb + c4 * 1024 +
                             (((unsigned)(4 * tid)) ^ (((unsigned)c4) << 4)));
        pr[2 * c4] = dot2f(gpv[c4], hv, 0.f);
        pr[2 * c4 + 1] = dot2f(gcv[c4], hv, 0.f);
      }
#pragma unroll
      for (int off = 32; off > 0; off >>= 1)
#pragma unroll
        for (int i = 0; i < 8; ++i) pr[i] += __shfl_down(pr[i], off);
      if (lane == 0) {
#pragma unroll
        for (int i = 0; i < 8; ++i) swred[wid][i] = pr[i];
      }
    }
    __syncthreads();  // (1): yredf + swred visible; h reads done before writes

    // ---- D. reduce over 4 waves + publish ----
    if (isV) {
      // thread tid: col = tid>>2, ch = tid&3 — consecutive LDS reads
      float y = yredf[tid] + yredf[256 + tid] + yredf[512 + tid] + yredf[768 + tid];
      float yp = __shfl_down(y, 4);  // partner col+1, same ch
      if ((tid & 4) == 0) {
        h2 pk; pk[0] = (f16)y; pk[1] = (f16)yp;
        unsigned lo; __builtin_memcpy(&lo, &pk, 4);
        __hip_atomic_store(
            yVp + (((size_t)grp * 2 + par) * 4 + (tid & 3)) * 256 + s * 32 + (tid >> 3),
            tagw | (u64)lo, __ATOMIC_RELAXED, __HIP_MEMORY_SCOPE_AGENT);
      }
    } else {
      // wave = chain, lane = col (64 cols); q . h partial for this slice
      const int lc = lane;
      float yq = yredf[lc * 4 + wid] + yredf[256 + lc * 4 + wid] +
                 yredf[512 + lc * 4 + wid] + yredf[768 + lc * 4 + wid];
      const int u = (s - 8) * 64 + lc;
      f16 hu = *(const f16*)(hpkb + wid * 1024 +
                             (((unsigned)(2 * u)) ^ (((unsigned)wid) << 4)));
      float p = yq * (float)hu;
#pragma unroll
      for (int off = 32; off > 0; off >>= 1) p += __shfl_down(p, off);
      if (lane == 0)
        __hip_atomic_store(
            s0p + (((size_t)grp * 2 + par) * 4 + wid) * 8 + (s - 8),
            tagw | (u64)__float_as_uint(p), __ATOMIC_RELAXED,
            __HIP_MEMORY_SCOPE_AGENT);
    }

    // ---- E. poll: 4 Vh pair-words (own u-pair, one per chain);
    //      threads 0-31 also poll one s0 partial ----
    const u64* vb = yVp + (((size_t)grp * 2 + par) * 4) * 256 + tid;
    u64 v0, v1, v2, v3, sw = tagw;
    const u64* sb = s0p + (((size_t)grp * 2 + par) * 4 + (tid >> 3)) * 8 + (tid & 7);
    for (;;) {
      v0 = __hip_atomic_load(vb, __ATOMIC_RELAXED, __HIP_MEMORY_SCOPE_AGENT);
      v1 = __hip_atomic_load(vb + 256, __ATOMIC_RELAXED, __HIP_MEMORY_SCOPE_AGENT);
      v2 = __hip_atomic_load(vb + 512, __ATOMIC_RELAXED, __HIP_MEMORY_SCOPE_AGENT);
      v3 = __hip_atomic_load(vb + 768, __ATOMIC_RELAXED, __HIP_MEMORY_SCOPE_AGENT);
      bool ok = (v0 >= tagw) & (v1 >= tagw) & (v2 >= tagw) & (v3 >= tagw);
      if (tid < 32) {
        sw = __hip_atomic_load(sb, __ATOMIC_RELAXED, __HIP_MEMORY_SCOPE_AGENT);
        ok = ok && (sw >= tagw);
      }
      if (ok) break;
      __builtin_amdgcn_s_sleep(1);
    }

    // ---- F. s0 assembly + softmax coefficients (threads 0-31 -> 4) ----
    if (tid < 32) {
      float sp = __uint_as_float((unsigned)sw);
      sp += __shfl_xor(sp, 1);
      sp += __shfl_xor(sp, 2);
      sp += __shfl_xor(sp, 4);
      if ((tid & 7) == 0) {
        const int c4 = tid >> 3;
        const float sv0 = sp * scale;
        const float sv1 = (swred[0][2 * c4] + swred[1][2 * c4] +
                           swred[2][2 * c4] + swred[3][2 * c4]) * scale;
        const float sv2 = (swred[0][2 * c4 + 1] + swred[1][2 * c4 + 1] +
                           swred[2][2 * c4 + 1] + swred[3][2 * c4 + 1]) * scale;
        const float mx = fmaxf(sv0, fmaxf(sv1, sv2));
        const float e0 = __expf(sv0 - mx), e1 = __expf(sv1 - mx),
                    e2 = __expf(sv2 - mx);
        const float inv = 1.f / (e0 + e1 + e2);
        aa[c4][0] = e0 * inv; aa[c4][1] = e1 * inv; aa[c4][2] = e2 * inv;
      }
    }
    __syncthreads();  // (2): aa visible

    // ---- G. h update: own u-pair for all 4 chains ----
    {
      u64 vw[4] = {v0, v1, v2, v3};
#pragma unroll
      for (int c4 = 0; c4 < 4; ++c4) {
        const float a0 = aa[c4][0], a1 = aa[c4][1], a2 = aa[c4][2];
        unsigned lo = (unsigned)vw[c4];
        h2 vh; __builtin_memcpy(&vh, &lo, 4);
        float hn0 = a0 * (float)vh[0] + a1 * (float)xp4[c4][0] + a2 * (float)xc4[c4][0];
        float hn1 = a0 * (float)vh[1] + a1 * (float)xp4[c4][1] + a2 * (float)xc4[c4][1];
        h2 hn; hn[0] = (f16)hn0; hn[1] = (f16)hn1;
        *(h2*)(hpkb + c4 * 1024 +
               (((unsigned)(4 * tid)) ^ (((unsigned)c4) << 4))) = hn;
        if (t == T - 1 && s == 0) {
          float* ob = out + ((size_t)grp * 4 + c4) * 512 + 2 * tid;
          ob[0] = hn0; ob[1] = hn1;
        }
      }
    }
    __syncthreads();  // (3): h writes visible for next step
  }
}

extern "C" void kernel_launch(void* const* d_in, const int* in_sizes, int n_in,
                              void* d_out, int out_size, void* d_ws,
                              size_t ws_size, hipStream_t stream) {
  const float* x = (const float*)d_in[0];     // [64][512][512]
  const float* Wq = (const float*)d_in[1];
  const float* Wk = (const float*)d_in[2];
  const float* Wv = (const float*)d_in[3];
  const float* Wrec = (const float*)d_in[4];
  float* out = (float*)d_out;                 // [64][512]

  char* ws = (char*)d_ws;
  f16* GXV = (f16*)ws;                        // [32768][1024] f16 = 64 MiB
  f16* Wt = (f16*)(ws + 67108864);            // [1024][512] f16 = 1 MiB
  f16* Wrk = (f16*)(ws + 68157440);           // 512 KiB
  f16* Wrq = (f16*)(ws + 68681728);           // 512 KiB (ybuf overlays after use)
  f16* WgT = (f16*)(ws + 69206016);           // 512 KiB
  u64* ybuf = (u64*)(ws + 68681728);          // 33792 u64 = 264 KiB

  // ---- weight combinations ----
  gemm128<AM_F32, BM_NN_F32, 0><<<16, 256, 0, stream>>>(Wrec, Wk, Wrk, 512, 512, 512, 0, 4);
  gemm128<AM_F32, BM_NN_F32, 0><<<16, 256, 0, stream>>>(Wrec, Wq, Wrq, 512, 512, 512, 0, 4);
  // Wt rows 0..511  = Wrv^T
  gemm128<AM_F32, BM_NN_F32, 1><<<16, 256, 0, stream>>>(Wrec, Wv, Wt, 512, 512, 512, 0, 4);
  // Wt rows 512..1023 = Wkq^T  (Wkq = Wrk@Wrq^T)
  gemm128<AM_F16, BM_BT_F16, 1><<<16, 256, 0, stream>>>(Wrk, Wrq, Wt, 512, 0, 512, 512, 4);
  // WgT = Wrk@Wq^T
  gemm128<AM_F16, BM_BT_F32, 0><<<16, 256, 0, stream>>>(Wrk, Wq, WgT, 512, 0, 512, 0, 4);
  // G and XV for all (b,t)
  gemm128<AM_F32, BM_BT_F16, 0><<<1024, 256, 0, stream>>>(x, WgT, GXV, 512, 0, 1024, 0, 4);
  gemm128<AM_F32, BM_NN_F32, 0><<<1024, 256, 0, stream>>>(x, Wv, GXV, 512, 512, 1024, 512, 4);

  // zero tagged buffer (after gemms that used the overlaid region)
  zero_ybuf<<<132, 256, 0, stream>>>(ybuf);

  // ---- sequential recurrence: cooperative, 256 WGs = 1 per CU ----
  const f16* WtC = Wt; const f16* GXVC = GXV;
  void* args[] = {(void*)&WtC, (void*)&GXVC, (void*)&ybuf, (void*)&out};
  dim3 grid(256), block(256);
  if (hipLaunchCooperativeKernel((const void*)seq_kernel, grid, block, args, 0,
                                 stream) != hipSuccess) {
    seq_kernel<<<grid, block, 0, stream>>>(WtC, GXVC, ybuf, out);
  }
}

// Round 11
// 1659.425 us; speedup vs baseline: 2.0101x; 1.1792x over previous
//
#include <hip/hip_runtime.h>

// ---------------------------------------------------------------------------
// Self_RNN forward, MI355X.
//   Wrv = Wrec@Wv ; Wrk = Wrec@Wk ; Wrq = Wrec@Wq ; Wkq = Wrk@Wrq^T
//   WgT = Wrk@Wq^T ; G[b,t] = x[b,t]@WgT^T ; XV[b,t] = x[b,t]@Wv
//   per step: y = h @ [Wrv | Wkq]  -> Vh = y[0:512], q = y[512:1024]
//             s0=(q.h)sc, s1=(h.G[t-1])sc, s2=(h.G[t])sc ; a=softmax(s)
//             h' = a0*Vh + a1*XV[t-1] + a2*XV[t]
// Sequential phase: 256 coop WGs = 16 groups (4 chains) x 16 slices (64 cols).
// Transport: agent-scope HIP atomics, tagged u64 {tag=t+1, payload}.
// R11: publish-EARLY — col-split MFMA (16 cols x full K per wave) so each
// wave publishes straight from its accumulators, before any barrier; q-slices
// publish per-wave s0 partials (no cross-wave sum on the publish path).
// ---------------------------------------------------------------------------

typedef _Float16 f16;
typedef _Float16 half8 __attribute__((ext_vector_type(8)));
typedef _Float16 h2 __attribute__((ext_vector_type(2)));
typedef float floatx4 __attribute__((ext_vector_type(4)));
typedef unsigned long long u64;

#define AM_F32 0
#define AM_F16 1
#define BM_NN_F32 0   // B  is [K][N] f32 (transpose-staged)
#define BM_BT_F16 1   // Bt is [N][K] f16
#define BM_BT_F32 2   // Bt is [N][K] f32

#if defined(__has_builtin)
#if __has_builtin(__builtin_amdgcn_fdot2)
#define HAS_FDOT2 1
#endif
#endif

__device__ inline float dot2f(h2 a, h2 b, float c) {
#ifdef HAS_FDOT2
  return __builtin_amdgcn_fdot2(a, b, c, false);
#else
  return c + (float)a[0] * (float)b[0] + (float)a[1] * (float)b[1];
#endif
}

// C[M,N] = A[M,K] @ B ; 128x128 tile, BK=32, 4 waves, MFMA f16.
// CT=0: C[row*ldc + coff + col]   CT=1: C[(coff+col)*ldc + row]
template<int AMODE, int BMODE, int CT>
__global__ __launch_bounds__(256)
void gemm128(const void* __restrict__ Ap, const void* __restrict__ Bp,
             f16* __restrict__ C, int K, int ldbnn, long ldc, long coff,
             int ntiles) {
  __shared__ f16 Al[128 * 32];
  __shared__ f16 Bl[128 * 32];
  const int tid = threadIdx.x;
  const int lane = tid & 63;
  const int wid = tid >> 6;
  const int wr = wid >> 1, wc = wid & 1;
  const int mt = blockIdx.x / ntiles, nt = blockIdx.x % ntiles;
  const long m0 = (long)mt * 128, n0 = (long)nt * 128;

  floatx4 acc[4][4];
#pragma unroll
  for (int m = 0; m < 4; ++m)
#pragma unroll
    for (int n = 0; n < 4; ++n) acc[m][n] = (floatx4){0.f, 0.f, 0.f, 0.f};

  for (int k0 = 0; k0 < K; k0 += 32) {
    __syncthreads();
#pragma unroll
    for (int i = 0; i < 2; ++i) {
      const int slot = i * 256 + tid;
      const int row = slot >> 2;
      const int kc = (slot & 3) * 8;
      if constexpr (AMODE == AM_F16) {
        const f16* Ag = (const f16*)Ap;
        half8 v = *(const half8*)(Ag + (m0 + row) * (long)K + k0 + kc);
        *(half8*)(Al + slot * 8) = v;
      } else {
        const float* Ag = (const float*)Ap;
        const float* p = Ag + (m0 + row) * (long)K + k0 + kc;
        float4 v0 = *(const float4*)(p);
        float4 v1 = *(const float4*)(p + 4);
        half8 h;
        h[0] = (f16)v0.x; h[1] = (f16)v0.y; h[2] = (f16)v0.z; h[3] = (f16)v0.w;
        h[4] = (f16)v1.x; h[5] = (f16)v1.y; h[6] = (f16)v1.z; h[7] = (f16)v1.w;
        *(half8*)(Al + slot * 8) = h;
      }
    }
    if constexpr (BMODE == BM_NN_F32) {
      const float* Bg = (const float*)Bp;
      const int nn = tid & 127;
      const int kh = (tid >> 7) * 16;
#pragma unroll
      for (int j = 0; j < 16; j += 2) {
        float b0 = Bg[(long)(k0 + kh + j) * ldbnn + n0 + nn];
        float b1 = Bg[(long)(k0 + kh + j + 1) * ldbnn + n0 + nn];
        h2 hv; hv[0] = (f16)b0; hv[1] = (f16)b1;
        *(h2*)(Bl + nn * 32 + kh + j) = hv;
      }
    } else {
#pragma unroll
      for (int i = 0; i < 2; ++i) {
        const int slot = i * 256 + tid;
        const int row = slot >> 2;
        const int kc = (slot & 3) * 8;
        if constexpr (BMODE == BM_BT_F16) {
          const f16* Bg = (const f16*)Bp;
          half8 v = *(const half8*)(Bg + (n0 + row) * (long)K + k0 + kc);
          *(half8*)(Bl + slot * 8) = v;
        } else {
          const float* Bg = (const float*)Bp;
          const float* p = Bg + (n0 + row) * (long)K + k0 + kc;
          float4 v0 = *(const float4*)(p);
          float4 v1 = *(const float4*)(p + 4);
          half8 h;
          h[0] = (f16)v0.x; h[1] = (f16)v0.y; h[2] = (f16)v0.z; h[3] = (f16)v0.w;
          h[4] = (f16)v1.x; h[5] = (f16)v1.y; h[6] = (f16)v1.z; h[7] = (f16)v1.w;
          *(half8*)(Bl + slot * 8) = h;
        }
      }
    }
    __syncthreads();
    const int frow = lane & 15;
    const int fkc = (lane >> 4) * 8;
    half8 af[4], bf[4];
#pragma unroll
    for (int m = 0; m < 4; ++m)
      af[m] = *(const half8*)(Al + (wr * 64 + m * 16 + frow) * 32 + fkc);
#pragma unroll
    for (int n = 0; n < 4; ++n)
      bf[n] = *(const half8*)(Bl + (wc * 64 + n * 16 + frow) * 32 + fkc);
#pragma unroll
    for (int m = 0; m < 4; ++m)
#pragma unroll
      for (int n = 0; n < 4; ++n)
        acc[m][n] = __builtin_amdgcn_mfma_f32_16x16x32_f16(af[m], bf[n],
                                                           acc[m][n], 0, 0, 0);
  }
  const int crow = (lane >> 4) * 4;
  const int ccol = lane & 15;
#pragma unroll
  for (int m = 0; m < 4; ++m)
#pragma unroll
    for (int n = 0; n < 4; ++n)
#pragma unroll
      for (int r = 0; r < 4; ++r) {
        long row = m0 + wr * 64 + m * 16 + crow + r;
        long col = n0 + wc * 64 + n * 16 + ccol;
        if constexpr (CT)
          C[(coff + col) * ldc + row] = (f16)acc[m][n][r];
        else
          C[row * ldc + coff + col] = (f16)acc[m][n][r];
      }
}

// zero tagged buffer: 36864 u64 (yVp 32768 + s0p 4096). MUST run every launch.
__global__ void zero_ybuf(u64* ybuf) {
  ybuf[(size_t)blockIdx.x * 256 + threadIdx.x] = 0ull;
}

// 256 WGs: wg = s*16 + grp. grp = chain group (chains 4grp..4grp+3),
// s = slice: s<8 -> Vh cols [s*64,s*64+64); s>=8 -> q cols [(s-8)*64 ...).
// yVp[16grp][2par][4ch][256 pairs] u64 {tag, 2xf16};
// s0p[16grp][2par][4ch][8 qslice x 4 wave] u64 {tag, f32 partial}.
__global__ __launch_bounds__(256, 1)
void seq_kernel(const f16* __restrict__ Wt, const f16* __restrict__ GXV,
                u64* __restrict__ ybuf, float* __restrict__ out) {
  const int wg = blockIdx.x;
  const int grp = wg & 15;
  const int s = wg >> 4;
  const int tid = threadIdx.x;
  const int lane = tid & 63;
  const int wid = tid >> 6;
  const int T = 512;

  __shared__ __align__(16) char wlds[64 * 1024];  // W slice [64col][512k] f16 XOR
  __shared__ __align__(16) char hpkb[16 * 1024];  // h [16r][512u] f16 XOR; r4-15=0
  __shared__ float swred[4][8];
  __shared__ float aa[4][4];                      // a0,a1,a2 per chain

  // ---- preload weight slice (rows s*64 .. s*64+63 of Wt) ----
  {
    const int col = tid >> 2;
    const int seg = (tid & 3) * 256;
    const unsigned key = ((unsigned)col & 7u) << 4;
    const char* src = (const char*)(Wt + (size_t)(s * 64 + col) * 512);
#pragma unroll
    for (int k = 0; k < 16; ++k) {
      half8 v = *(const half8*)(src + seg + k * 16);
      *(half8*)(wlds + col * 1024 + ((unsigned)(seg + k * 16) ^ key)) = v;
    }
  }
  // ---- zero h (all 16 rows; rows 4-15 stay zero forever) ----
#pragma unroll
  for (int i = 0; i < 4; ++i)
    *(floatx4*)(hpkb + tid * 64 + i * 16) = (floatx4){0.f, 0.f, 0.f, 0.f};
  __syncthreads();

  const float scale = 0.04419417382415922f;  // 1/sqrt(512)
  const bool isV = (s < 8);
  u64* const yVp = ybuf;
  u64* const s0p = ybuf + 32768;

  // MFMA fragment addressing: A row (chain) = B local-col-row = lane&15
  const int arow = lane & 15;
  const unsigned abkey = ((unsigned)(arow & 7)) << 4;
  const int kseg = (lane >> 4) * 16;  // byte sub-offset within each 64B k-step

  for (int t = 0; t < T; ++t) {
    const int par = t & 1;
    const u64 tagw = ((u64)(unsigned)(t + 1)) << 32;

    // ---- A. hoisted global loads (own u-pair = {2tid, 2tid+1} per chain) ----
    h2 xc4[4], xp4[4], gcv[4], gpv[4];
#pragma unroll
    for (int c4 = 0; c4 < 4; ++c4) {
      const f16* rowc = GXV + (((size_t)grp * 4 + c4) * T + t) * 1024;
      gcv[c4] = *(const h2*)(rowc + 2 * tid);
      xc4[c4] = *(const h2*)(rowc + 512 + 2 * tid);
      h2 z; z[0] = (f16)0.f; z[1] = (f16)0.f;
      gpv[c4] = z; xp4[c4] = z;
      if (t > 0) {
        gpv[c4] = *(const h2*)(rowc - 1024 + 2 * tid);
        xp4[c4] = *(const h2*)(rowc - 512 + 2 * tid);
      }
    }

    // ---- B. MFMA matvec: this wave's 16 cols, FULL K=512 (no x-wave reduce) --
    floatx4 acc = (floatx4){0.f, 0.f, 0.f, 0.f};
#pragma unroll
    for (int ks = 0; ks < 16; ++ks) {
      const unsigned ko = (unsigned)(ks * 64 + kseg);
      half8 av = *(const half8*)(hpkb + arow * 1024 + (ko ^ abkey));
      half8 bv = *(const half8*)(wlds + (wid * 16 + arow) * 1024 + (ko ^ abkey));
      acc = __builtin_amdgcn_mfma_f32_16x16x32_f16(av, bv, acc, 0, 0, 0);
    }

    // ---- C. publish IMMEDIATELY from accumulators (before any barrier) ----
    if (isV) {
      // lanes 0-15 hold the 4 real chains for col = wid*16 + lane
#pragma unroll
      for (int r = 0; r < 4; ++r) {
        float v = acc[r];
        float vp = __shfl_xor(v, 1);
        if (lane < 16 && !(lane & 1)) {
          h2 pk; pk[0] = (f16)v; pk[1] = (f16)vp;
          unsigned lo; __builtin_memcpy(&lo, &pk, 4);
          __hip_atomic_store(
              yVp + (((size_t)grp * 2 + par) * 4 + r) * 256 + s * 32 + wid * 8 +
                  (lane >> 1),
              tagw | (u64)lo, __ATOMIC_RELAXED, __HIP_MEMORY_SCOPE_AGENT);
        }
      }
    } else {
      // per-wave s0 partial: q[16 cols of this wave] . h[same cols]
      float p[4];
      const int c = (s - 8) * 64 + wid * 16 + arow;
#pragma unroll
      for (int r = 0; r < 4; ++r) {
        f16 hv = *(const f16*)(hpkb + r * 1024 +
                               (((unsigned)(2 * c)) ^ (((unsigned)r) << 4)));
        p[r] = acc[r] * (float)hv;  // lanes>=16: acc rows 4-15 are zero
      }
#pragma unroll
      for (int off = 32; off > 0; off >>= 1)
#pragma unroll
        for (int r = 0; r < 4; ++r) p[r] += __shfl_down(p[r], off);
      if (lane == 0) {
#pragma unroll
        for (int r = 0; r < 4; ++r)
          __hip_atomic_store(
              s0p + (((size_t)grp * 2 + par) * 4 + r) * 32 + (s - 8) * 4 + wid,
              tagw | (u64)__float_as_uint(p[r]), __ATOMIC_RELAXED,
              __HIP_MEMORY_SCOPE_AGENT);
      }
    }

    // ---- D. s1/s2 partials (after publish — needed only post-poll) ----
    {
      float pr[8];
#pragma unroll
      for (int c4 = 0; c4 < 4; ++c4) {
        h2 hv = *(const h2*)(hpkb + c4 * 1024 +
                             (((unsigned)(4 * tid)) ^ (((unsigned)c4) << 4)));
        pr[2 * c4] = dot2f(gpv[c4], hv, 0.f);
        pr[2 * c4 + 1] = dot2f(gcv[c4], hv, 0.f);
      }
#pragma unroll
      for (int off = 32; off > 0; off >>= 1)
#pragma unroll
        for (int i = 0; i < 8; ++i) pr[i] += __shfl_down(pr[i], off);
      if (lane == 0) {
#pragma unroll
        for (int i = 0; i < 8; ++i) swred[wid][i] = pr[i];
      }
    }
    __syncthreads();  // (1): swred visible; h reads done before writes

    // ---- E. poll: 4 Vh pair-words; threads 0-127 also one s0 partial ----
    const u64* vb = yVp + (((size_t)grp * 2 + par) * 4) * 256 + tid;
    const u64* sb = s0p + (((size_t)grp * 2 + par) * 4 + (tid >> 5)) * 32 + (tid & 31);
    u64 v0, v1, v2, v3, sw = tagw;
    for (;;) {
      v0 = __hip_atomic_load(vb, __ATOMIC_RELAXED, __HIP_MEMORY_SCOPE_AGENT);
      v1 = __hip_atomic_load(vb + 256, __ATOMIC_RELAXED, __HIP_MEMORY_SCOPE_AGENT);
      v2 = __hip_atomic_load(vb + 512, __ATOMIC_RELAXED, __HIP_MEMORY_SCOPE_AGENT);
      v3 = __hip_atomic_load(vb + 768, __ATOMIC_RELAXED, __HIP_MEMORY_SCOPE_AGENT);
      bool ok = (v0 >= tagw) & (v1 >= tagw) & (v2 >= tagw) & (v3 >= tagw);
      if (tid < 128) {
        sw = __hip_atomic_load(sb, __ATOMIC_RELAXED, __HIP_MEMORY_SCOPE_AGENT);
        ok = ok && (sw >= tagw);
      }
      if (ok) break;
      __builtin_amdgcn_s_sleep(1);
    }

    // ---- F. s0 assembly (32 partials per chain) + softmax coefficients ----
    if (tid < 128) {
      float sp = __uint_as_float((unsigned)sw);
      sp += __shfl_xor(sp, 1);
      sp += __shfl_xor(sp, 2);
      sp += __shfl_xor(sp, 4);
      sp += __shfl_xor(sp, 8);
      sp += __shfl_xor(sp, 16);
      if ((tid & 31) == 0) {
        const int c4 = tid >> 5;
        const float sv0 = sp * scale;
        const float sv1 = (swred[0][2 * c4] + swred[1][2 * c4] +
                           swred[2][2 * c4] + swred[3][2 * c4]) * scale;
        const float sv2 = (swred[0][2 * c4 + 1] + swred[1][2 * c4 + 1] +
                           swred[2][2 * c4 + 1] + swred[3][2 * c4 + 1]) * scale;
        const float mx = fmaxf(sv0, fmaxf(sv1, sv2));
        const float e0 = __expf(sv0 - mx), e1 = __expf(sv1 - mx),
                    e2 = __expf(sv2 - mx);
        const float inv = 1.f / (e0 + e1 + e2);
        aa[c4][0] = e0 * inv; aa[c4][1] = e1 * inv; aa[c4][2] = e2 * inv;
      }
    }
    __syncthreads();  // (2): aa visible

    // ---- G. h update: own u-pair for all 4 chains ----
    {
      u64 vw[4] = {v0, v1, v2, v3};
#pragma unroll
      for (int c4 = 0; c4 < 4; ++c4) {
        const float a0 = aa[c4][0], a1 = aa[c4][1], a2 = aa[c4][2];
        unsigned lo = (unsigned)vw[c4];
        h2 vh; __builtin_memcpy(&vh, &lo, 4);
        float hn0 = a0 * (float)vh[0] + a1 * (float)xp4[c4][0] + a2 * (float)xc4[c4][0];
        float hn1 = a0 * (float)vh[1] + a1 * (float)xp4[c4][1] + a2 * (float)xc4[c4][1];
        h2 hn; hn[0] = (f16)hn0; hn[1] = (f16)hn1;
        *(h2*)(hpkb + c4 * 1024 +
               (((unsigned)(4 * tid)) ^ (((unsigned)c4) << 4))) = hn;
        if (t == T - 1 && s == 0) {
          float* ob = out + ((size_t)grp * 4 + c4) * 512 + 2 * tid;
          ob[0] = hn0; ob[1] = hn1;
        }
      }
    }
    __syncthreads();  // (3): h writes visible for next step
  }
}

extern "C" void kernel_launch(void* const* d_in, const int* in_sizes, int n_in,
                              void* d_out, int out_size, void* d_ws,
                              size_t ws_size, hipStream_t stream) {
  const float* x = (const float*)d_in[0];     // [64][512][512]
  const float* Wq = (const float*)d_in[1];
  const float* Wk = (const float*)d_in[2];
  const float* Wv = (const float*)d_in[3];
  const float* Wrec = (const float*)d_in[4];
  float* out = (float*)d_out;                 // [64][512]

  char* ws = (char*)d_ws;
  f16* GXV = (f16*)ws;                        // [32768][1024] f16 = 64 MiB
  f16* Wt = (f16*)(ws + 67108864);            // [1024][512] f16 = 1 MiB
  f16* Wrk = (f16*)(ws + 68157440);           // 512 KiB
  f16* Wrq = (f16*)(ws + 68681728);           // 512 KiB (ybuf overlays after use)
  f16* WgT = (f16*)(ws + 69206016);           // 512 KiB
  u64* ybuf = (u64*)(ws + 68681728);          // 36864 u64 = 288 KiB

  // ---- weight combinations ----
  gemm128<AM_F32, BM_NN_F32, 0><<<16, 256, 0, stream>>>(Wrec, Wk, Wrk, 512, 512, 512, 0, 4);
  gemm128<AM_F32, BM_NN_F32, 0><<<16, 256, 0, stream>>>(Wrec, Wq, Wrq, 512, 512, 512, 0, 4);
  // Wt rows 0..511  = Wrv^T
  gemm128<AM_F32, BM_NN_F32, 1><<<16, 256, 0, stream>>>(Wrec, Wv, Wt, 512, 512, 512, 0, 4);
  // Wt rows 512..1023 = Wkq^T  (Wkq = Wrk@Wrq^T)
  gemm128<AM_F16, BM_BT_F16, 1><<<16, 256, 0, stream>>>(Wrk, Wrq, Wt, 512, 0, 512, 512, 4);
  // WgT = Wrk@Wq^T
  gemm128<AM_F16, BM_BT_F32, 0><<<16, 256, 0, stream>>>(Wrk, Wq, WgT, 512, 0, 512, 0, 4);
  // G and XV for all (b,t)
  gemm128<AM_F32, BM_BT_F16, 0><<<1024, 256, 0, stream>>>(x, WgT, GXV, 512, 0, 1024, 0, 4);
  gemm128<AM_F32, BM_NN_F32, 0><<<1024, 256, 0, stream>>>(x, Wv, GXV, 512, 512, 1024, 512, 4);

  // zero tagged buffer (after gemms that used the overlaid region)
  zero_ybuf<<<144, 256, 0, stream>>>(ybuf);

  // ---- sequential recurrence: cooperative, 256 WGs = 1 per CU ----
  const f16* WtC = Wt; const f16* GXVC = GXV;
  void* args[] = {(void*)&WtC, (void*)&GXVC, (void*)&ybuf, (void*)&out};
  dim3 grid(256), block(256);
  if (hipLaunchCooperativeKernel((const void*)seq_kernel, grid, block, args, 0,
                                 stream) != hipSuccess) {
    seq_kernel<<<grid, block, 0, stream>>>(WtC, GXVC, ybuf, out);
  }
}